// Round 4
// baseline (93.073 us; speedup 1.0000x reference)
//
#include <hip/hip_runtime.h>

#define ALPHA 0.3f
#define NT    50
#define B_    16
#define S_    160
#define RR    40
#define Q_    (RR / 4)            // 10 float4 per (pair) rel row
#define NROW  (B_ * S_)           // 2560
#define NPAIR (B_ * S_ * S_)      // 409600
#define NSEG  (NT * NT)           // 2500
#define NREL  (NPAIR * RR)        // 16384000
#define NCOL  (NT * RR + NT)      // 2050 compact floats per C row
#define CW    2052                // padded C row stride (floats), 8208B (16B-aligned)

__global__ void zero_tab(float* __restrict__ tab, int n) {
    int i = blockIdx.x * blockDim.x + threadIdx.x;
    if (i < n) tab[i] = 0.0f;
}

// ---- stage 1: one block per (b,t1) group ----
// Builds the batch's tag->positions lists in LDS (counting sort, deterministic),
// then each thread owns output cells and gather-reduces in registers.
// TO_C=1: write compact partial row C[t1][b][.]   TO_C=0: atomicAdd into tab (fallback)
template <int TO_C>
__global__ __launch_bounds__(256) void stage1g(const float* __restrict__ a_arc,
                                               const float4* __restrict__ a_rel4,
                                               const int* __restrict__ adds,
                                               float* __restrict__ C,
                                               float* __restrict__ tab_arc,
                                               float* __restrict__ tab_rel) {
    __shared__ int s_tags[S_];
    __shared__ int s_cnt[NT];
    __shared__ int s_start[NT + 1];
    __shared__ int s_list[S_];
    int blk = blockIdx.x;            // b*NT + t1
    int b   = blk / NT;
    int t1  = blk - b * NT;
    int tid = threadIdx.x;

    if (tid < S_) s_tags[tid] = adds[b * S_ + tid];
    __syncthreads();
    if (tid < NT) {
        int c = 0;
        for (int i = 0; i < S_; i++) c += (s_tags[i] == tid);
        s_cnt[tid] = c;
    }
    __syncthreads();
    if (tid == 0) {
        int s = 0;
        for (int t = 0; t < NT; t++) { s_start[t] = s; s += s_cnt[t]; }
        s_start[NT] = s;
    }
    __syncthreads();
    if (tid < NT) {
        int slot = s_start[tid];
        for (int i = 0; i < S_; i++)
            if (s_tags[i] == tid) s_list[slot++] = i;
    }
    __syncthreads();

    int r0 = s_start[t1], r1 = s_start[t1 + 1];   // p1 positions with tag t1

    // rel cells: (t2, q) — 500 of them
    for (int cell = tid; cell < NT * Q_; cell += 256) {
        int t2 = cell / Q_;
        int q  = cell - t2 * Q_;
        int c0 = s_start[t2], c1 = s_start[t2 + 1];
        float4 acc = make_float4(0.f, 0.f, 0.f, 0.f);
        for (int i = r0; i < r1; ++i) {
            const float4* arow = a_rel4 + (size_t)(b * S_ + s_list[i]) * (S_ * Q_);
            for (int j = c0; j < c1; ++j) {
                float4 v = arow[s_list[j] * Q_ + q];
                acc.x += v.x; acc.y += v.y; acc.z += v.z; acc.w += v.w;
            }
        }
        if (TO_C) {
            ((float4*)(C + (size_t)(t1 * B_ + b) * CW))[cell] = acc;
        } else {
            float* dst = tab_rel + (size_t)t1 * (NT * RR) + cell * 4;
            atomicAdd(dst + 0, acc.x); atomicAdd(dst + 1, acc.y);
            atomicAdd(dst + 2, acc.z); atomicAdd(dst + 3, acc.w);
        }
    }
    // arc cells: t2 — 50 of them
    if (tid < NT) {
        int t2 = tid;
        int c0 = s_start[t2], c1 = s_start[t2 + 1];
        float acc = 0.f;
        for (int i = r0; i < r1; ++i) {
            const float* aarow = a_arc + (size_t)(b * S_ + s_list[i]) * S_;
            for (int j = c0; j < c1; ++j) acc += aarow[s_list[j]];
        }
        if (TO_C) C[(size_t)(t1 * B_ + b) * CW + NT * RR + t2] = acc;
        else      atomicAdd(&tab_arc[t1 * NT + t2], acc);
    }
}

// ---- stage 2: sum the 16 batch partials per t1 (no atomics, deterministic) ----
__global__ __launch_bounds__(256) void stage2g(const float* __restrict__ C,
                                               float* __restrict__ tab_arc,
                                               float* __restrict__ tab_rel) {
    int t1 = blockIdx.y;
    int c  = blockIdx.x * 256 + threadIdx.x;
    if (c >= NCOL) return;
    const float* base = C + (size_t)t1 * B_ * CW + c;
    float acc = 0.f;
#pragma unroll
    for (int b = 0; b < B_; ++b) acc += base[(size_t)b * CW];
    if (c < NT * RR) tab_rel[t1 * (NT * RR) + c] = acc;
    else             tab_arc[t1 * NT + (c - NT * RR)] = acc;
}

// ---- fused apply: one block per (b,p1) row ----
__global__ __launch_bounds__(256) void apply_fused(const float* __restrict__ s_arc,
                                                   const float4* __restrict__ s_rel4,
                                                   const int* __restrict__ pos,
                                                   const float* __restrict__ tab_arc,
                                                   const float4* __restrict__ tab_rel4,
                                                   float* __restrict__ out_arc,
                                                   float4* __restrict__ out_rel4) {
    __shared__ int s_pos[S_];
    int row = blockIdx.x;            // b*S_ + p1
    int b   = row / S_;
    int p1  = row - b * S_;
    int tid = threadIdx.x;
    if (tid < S_) s_pos[tid] = pos[b * S_ + tid];
    __syncthreads();
    int base = s_pos[p1] * NT;

    const float4* srow = s_rel4  + (size_t)row * (S_ * Q_);
    float4*       orow = out_rel4 + (size_t)row * (S_ * Q_);
    for (int e = tid; e < S_ * Q_; e += 256) {
        int p2 = e / Q_;
        int q  = e - p2 * Q_;
        float4 sv = srow[e];
        float4 tv = tab_rel4[(base + s_pos[p2]) * Q_ + q];
        float4 o;
        o.x = sv.x + ALPHA * tv.x;
        o.y = sv.y + ALPHA * tv.y;
        o.z = sv.z + ALPHA * tv.z;
        o.w = sv.w + ALPHA * tv.w;
        orow[e] = o;
    }
    if (tid < S_) {
        out_arc[row * S_ + tid] = s_arc[row * S_ + tid]
                                + ALPHA * tab_arc[base + s_pos[tid]];
    }
}

extern "C" void kernel_launch(void* const* d_in, const int* in_sizes, int n_in,
                              void* d_out, int out_size, void* d_ws, size_t ws_size,
                              hipStream_t stream) {
    const float*  a_arc = (const float*)d_in[0];
    const float4* a_rel = (const float4*)d_in[1];
    const float*  s_arc = (const float*)d_in[2];
    const float4* s_rel = (const float4*)d_in[3];
    const int*    adds  = (const int*)d_in[4];
    const int*    pos   = (const int*)d_in[5];

    // workspace layout
    float* tab_arc = (float*)d_ws;                     // NSEG
    float* tab_rel = tab_arc + NSEG;                   // NSEG*RR
    float* C       = tab_rel + NSEG * RR;              // NT*B_*CW floats
    C = (float*)(((uintptr_t)C + 15) & ~(uintptr_t)15);

    size_t need_tab  = (size_t)(NSEG * (RR + 1)) * 4;
    size_t need_full = need_tab + 16 + (size_t)NT * B_ * CW * 4;

    float*  out_arc = (float*)d_out;                   // NPAIR
    float4* out_rel = (float4*)(out_arc + NPAIR);      // NREL/4

    const int BLK = 256;

    if (ws_size >= need_full) {
        // deterministic, zero atomics anywhere
        stage1g<1><<<B_ * NT, 256, 0, stream>>>(a_arc, a_rel, adds, C, nullptr, nullptr);
        dim3 g2((NCOL + 255) / 256, NT);
        stage2g<<<g2, 256, 0, stream>>>(C, tab_arc, tab_rel);
    } else {
        int n_tab = NSEG * (RR + 1);
        zero_tab<<<(n_tab + BLK - 1) / BLK, BLK, 0, stream>>>(tab_arc, n_tab);
        stage1g<0><<<B_ * NT, 256, 0, stream>>>(a_arc, a_rel, adds, nullptr, tab_arc, tab_rel);
    }

    apply_fused<<<NROW, 256, 0, stream>>>(s_arc, s_rel, pos, tab_arc,
                                          (const float4*)tab_rel, out_arc, out_rel);
}

// Round 5
// 82.296 us; speedup vs baseline: 1.1310x; 1.1310x over previous
//
#include <hip/hip_runtime.h>

#define ALPHA 0.3f
#define NT    50
#define B_    16
#define S_    160
#define RR    40
#define Q_    (RR / 4)            // 10 float4 per rel row-pair
#define NROW  (B_ * S_)           // 2560
#define NPAIR (B_ * S_ * S_)      // 409600
#define NSEG  (NT * NT)           // 2500
#define NREL  (NPAIR * RR)        // 16384000
#define NCOL  (NT * RR + NT)      // 2050 compact floats per C row
#define CW    2052                // padded C row stride (floats), 8208B (16B-aligned)

__global__ void zero_tab(float* __restrict__ tab, int n) {
    int i = blockIdx.x * blockDim.x + threadIdx.x;
    if (i < n) tab[i] = 0.0f;
}

// ---- per-batch position lists: deterministic counting sort of adds[b][:] ----
__global__ void build_lists(const int* __restrict__ adds,
                            int* __restrict__ colstart,   // [B_][64]
                            int* __restrict__ collist) {  // [B_][S_]
    __shared__ int tags[S_];
    __shared__ int cnt[NT];
    __shared__ int start[NT + 1];
    int b   = blockIdx.x;
    int tid = threadIdx.x;
    if (tid < S_) tags[tid] = adds[b * S_ + tid];
    __syncthreads();
    if (tid < NT) {
        int c = 0;
        for (int i = 0; i < S_; i++) c += (tags[i] == tid);
        cnt[tid] = c;
    }
    __syncthreads();
    if (tid == 0) {
        int s = 0;
        for (int t = 0; t < NT; t++) { start[t] = s; s += cnt[t]; }
        start[NT] = s;
    }
    __syncthreads();
    if (tid <= NT) colstart[b * 64 + tid] = start[tid];
    if (tid < NT) {
        int slot = start[tid];
        for (int i = 0; i < S_; i++)
            if (tags[i] == tid) collist[b * S_ + slot++] = i;
    }
}

// ---- stage 1: per-(b,p1)-row gather-reduce, register accumulation, NO atomics ----
// TO_C=1: write compact partial row to C.  TO_C=0: atomic-flush to tab (fallback).
template <int TO_C>
__global__ __launch_bounds__(256) void stage1(const float* __restrict__ a_arc,
                                              const float4* __restrict__ a_rel4,
                                              const int* __restrict__ adds,
                                              const int* __restrict__ colstart,
                                              const int* __restrict__ collist,
                                              float* __restrict__ C,
                                              float* __restrict__ tab_arc,
                                              float* __restrict__ tab_rel) {
    __shared__ int s_start[NT + 1];
    __shared__ int s_list[S_];
    int row = blockIdx.x;            // b*S_ + p1
    int b   = row / S_;
    int tid = threadIdx.x;
    if (tid <= NT) s_start[tid] = colstart[b * 64 + tid];
    if (tid < S_)  s_list[tid]  = collist[b * S_ + tid];
    __syncthreads();

    const float4* arow  = a_rel4 + (size_t)row * (S_ * Q_);
    const float*  aarow = a_arc + (size_t)row * S_;
    int t1 = TO_C ? 0 : adds[row];

    // rel: 500 float4 cells (t2, q)
    for (int cell = tid; cell < NT * Q_; cell += 256) {
        int t2 = cell / Q_;
        int q  = cell - t2 * Q_;
        float4 acc = make_float4(0.f, 0.f, 0.f, 0.f);
        int e1 = s_start[t2 + 1];
        for (int e = s_start[t2]; e < e1; ++e) {
            float4 v = arow[s_list[e] * Q_ + q];
            acc.x += v.x; acc.y += v.y; acc.z += v.z; acc.w += v.w;
        }
        if (TO_C) {
            ((float4*)(C + (size_t)row * CW))[cell] = acc;
        } else {
            float* dst = tab_rel + (size_t)t1 * (NT * RR) + cell * 4;
            atomicAdd(dst + 0, acc.x); atomicAdd(dst + 1, acc.y);
            atomicAdd(dst + 2, acc.z); atomicAdd(dst + 3, acc.w);
        }
    }
    // arc: 50 cells
    if (tid < NT) {
        float acc = 0.f;
        int e1 = s_start[tid + 1];
        for (int e = s_start[tid]; e < e1; ++e) acc += aarow[s_list[e]];
        if (TO_C) C[(size_t)row * CW + NT * RR + tid] = acc;
        else      atomicAdd(tab_arc + t1 * NT + tid, acc);
    }
}

// ---- stage 2: reduce C rows grouped by t1 via per-batch lists, NO atomics ----
__global__ __launch_bounds__(256) void stage2(const float* __restrict__ C,
                                              const int* __restrict__ colstart,
                                              const int* __restrict__ collist,
                                              float* __restrict__ tab_arc,
                                              float* __restrict__ tab_rel) {
    int t1 = blockIdx.y;
    int c  = blockIdx.x * 256 + threadIdx.x;
    if (c >= NCOL) return;
    float acc = 0.f;
    for (int b = 0; b < B_; b++) {
        int s0 = colstart[b * 64 + t1], s1 = colstart[b * 64 + t1 + 1];
        for (int j = s0; j < s1; j++) {
            int row = b * S_ + collist[b * S_ + j];
            acc += C[(size_t)row * CW + c];
        }
    }
    if (c < NT * RR) tab_rel[t1 * (NT * RR) + c] = acc;
    else             tab_arc[t1 * NT + (c - NT * RR)] = acc;
}

// ---- fused apply: one block per (b,p1) row ----
__global__ __launch_bounds__(256) void apply_fused(const float* __restrict__ s_arc,
                                                   const float4* __restrict__ s_rel4,
                                                   const int* __restrict__ pos,
                                                   const float* __restrict__ tab_arc,
                                                   const float4* __restrict__ tab_rel4,
                                                   float* __restrict__ out_arc,
                                                   float4* __restrict__ out_rel4) {
    __shared__ int s_pos[S_];
    int row = blockIdx.x;            // b*S_ + p1
    int b   = row / S_;
    int p1  = row - b * S_;
    int tid = threadIdx.x;
    if (tid < S_) s_pos[tid] = pos[b * S_ + tid];
    __syncthreads();
    int base = s_pos[p1] * NT;

    const float4* srow = s_rel4   + (size_t)row * (S_ * Q_);
    float4*       orow = out_rel4 + (size_t)row * (S_ * Q_);
    for (int e = tid; e < S_ * Q_; e += 256) {
        int p2 = e / Q_;
        int q  = e - p2 * Q_;
        float4 sv = srow[e];
        float4 tv = tab_rel4[(base + s_pos[p2]) * Q_ + q];
        float4 o;
        o.x = sv.x + ALPHA * tv.x;
        o.y = sv.y + ALPHA * tv.y;
        o.z = sv.z + ALPHA * tv.z;
        o.w = sv.w + ALPHA * tv.w;
        orow[e] = o;
    }
    if (tid < S_) {
        out_arc[row * S_ + tid] = s_arc[row * S_ + tid]
                                + ALPHA * tab_arc[base + s_pos[tid]];
    }
}

extern "C" void kernel_launch(void* const* d_in, const int* in_sizes, int n_in,
                              void* d_out, int out_size, void* d_ws, size_t ws_size,
                              hipStream_t stream) {
    const float*  a_arc = (const float*)d_in[0];
    const float4* a_rel = (const float4*)d_in[1];
    const float*  s_arc = (const float*)d_in[2];
    const float4* s_rel = (const float4*)d_in[3];
    const int*    adds  = (const int*)d_in[4];
    const int*    pos   = (const int*)d_in[5];

    // workspace layout
    float* tab_arc  = (float*)d_ws;                    // NSEG
    float* tab_rel  = tab_arc + NSEG;                  // NSEG*RR
    int*   colstart = (int*)(tab_rel + NSEG * RR);     // B_*64
    int*   collist  = colstart + B_ * 64;              // B_*S_
    float* C        = (float*)(collist + B_ * S_);     // NROW*CW
    C = (float*)(((uintptr_t)C + 15) & ~(uintptr_t)15);

    size_t need_lists = (size_t)(NSEG * (RR + 1)) * 4
                      + (size_t)(B_ * 64 + B_ * S_) * 4 + 16;
    size_t need_full  = need_lists + (size_t)NROW * CW * 4;

    float*  out_arc = (float*)d_out;                   // NPAIR
    float4* out_rel = (float4*)(out_arc + NPAIR);      // NREL/4

    const int BLK = 256;

    build_lists<<<B_, 192, 0, stream>>>(adds, colstart, collist);

    if (ws_size >= need_full) {
        // deterministic two-stage path, zero atomics anywhere
        stage1<1><<<NROW, 256, 0, stream>>>(a_arc, a_rel, adds, colstart, collist,
                                            C, nullptr, nullptr);
        dim3 g2((NCOL + 255) / 256, NT);
        stage2<<<g2, 256, 0, stream>>>(C, colstart, collist, tab_arc, tab_rel);
    } else {
        int n_tab = NSEG * (RR + 1);
        zero_tab<<<(n_tab + BLK - 1) / BLK, BLK, 0, stream>>>(tab_arc, n_tab);
        stage1<0><<<NROW, 256, 0, stream>>>(a_arc, a_rel, adds, colstart, collist,
                                            nullptr, tab_arc, tab_rel);
    }

    apply_fused<<<NROW, 256, 0, stream>>>(s_arc, s_rel, pos, tab_arc,
                                          (const float4*)tab_rel, out_arc, out_rel);
}